// Round 13
// baseline (1223.519 us; speedup 1.0000x reference)
//
#include <hip/hip_runtime.h>

// DynamicRNNEncoder on MI355X — round 13.
// R12 anchor (1162us) + two surgical deltas:
//  (1) merged tiled f16 DynHist [t][g][b][4hd|4cd]: dyn publish = one fully
//      covered contiguous 1KB burst/block (was 8B+16B scattered partial-line);
//      unconditional store (static slots provably never read); unified
//      base+stride consumer addressing (embT/DynHist/init).
//  (2) out store removed from the loop; bulk out pass after the t-loop reads
//      the f16 Hhist history back (own data only, no cross-block dep).

typedef _Float16 f16;
typedef _Float16 f16x4 __attribute__((ext_vector_type(4)));
typedef _Float16 f16x8 __attribute__((ext_vector_type(8)));
typedef float f32x4 __attribute__((ext_vector_type(4)));

#define B_ 64
#define T_ 256
#define H_ 512
#define EN_ 256
#define ET_ 256
#define D_ 256
#define VN_ 300
#define VS_ 100

#define NB_MAIN_ 128   // 4 main units (16 gate rows) each
#define NB_DYN_ 64     // 4 dyn units each
#define NBLK_ 192
#define NTHR_ 256
#define NSH_ 64        // barrier counter shards (64B apart)
#define PER_SHARD_ (NBLK_ / NSH_)   // 3
#define POLL_CAP_ (1u << 22)

// ---- workspace layout (bytes) ----
static constexpr size_t OFF_CNT  = 0;                                   // 4KB counters
static constexpr size_t OFF_EMBN = 4096;                                // embN f16  [300][256]
static constexpr size_t OFF_EMBT = OFF_EMBN + (size_t)VN_ * EN_ * 2;    // embT f16  [100][256] (== tiled [100][64][4])
static constexpr size_t OFF_DIT  = OFF_EMBT + (size_t)VS_ * ET_ * 2;    // dyn init tiled [64][8] f16 (hd|cd)
static constexpr size_t OFF_PREV = OFF_DIT + 1024;                      // prev int32 [T][B]
static constexpr size_t OFF_HH   = OFF_PREV + (size_t)T_ * B_ * 4;      // Hhist f16 tiled [T+1][128][64][4]
static constexpr size_t OFF_DH   = OFF_HH + (size_t)(T_ + 1) * B_ * H_ * 2; // DynHist f16 [T][64][64][8]
static constexpr size_t WS_NEED  = OFF_DH + (size_t)T_ * 64 * 64 * 8 * 2;   // ~33.9 MB

struct RnnParams {
  const int* n_input; const int* t_input; const int* s2d;
  const float* W_ih; const float* W_hh; const float* b_ih; const float* b_hh;
  const float* Wd_ih; const float* Wd_hh; const float* bd_ih; const float* bd_hh;
  const float* cell_init;
  const f16* embN16; const f16* embT16; const f16* dynT;
  const int* prev;
  f16* Hhist; f16* DynHist;
  float* out; unsigned* cnt;
};

__device__ __forceinline__ float sigm(float x) { return 1.f / (1.f + __expf(-x)); }
__device__ __forceinline__ float tanh_fast(float x) {
  float e = __expf(2.f * x);
  return 1.f - 2.f / (e + 1.f);
}

// ---- coherent-point helpers ----
__device__ __forceinline__ void cstore8(void* p, unsigned long long v) {
  __hip_atomic_store((unsigned long long*)p, v, __ATOMIC_RELAXED,
                     __HIP_MEMORY_SCOPE_AGENT);
}
__device__ __forceinline__ void cstore16h(void* p, f16x8 v) {
  asm volatile("global_store_dwordx4 %0, %1, off sc0 sc1"
               :: "v"(p), "v"(v) : "memory");
}
__device__ __forceinline__ f16x4 scload8h(const f16* p) {
  f16x4 v;
  asm volatile("global_load_dwordx2 %0, %1, off sc0 sc1\n\ts_waitcnt vmcnt(0)"
               : "=&v"(v) : "v"(p) : "memory");
  return v;
}
// lgkm-only block barrier (no vmcnt drain on the critical path)
__device__ __forceinline__ void lds_barrier() {
  asm volatile("s_waitcnt lgkmcnt(0)\n\ts_barrier" ::: "memory");
}

// ---- setup: f16 conversions, tiled Hhist[0] init, init-row, counter reset ----
__global__ void setup_kernel(const float* embN, const float* embT,
                             const float* hid_init, const float* dyn_init_h,
                             const float* dyn_init_c,
                             f16* embN16, f16* embT16, f16* dynT,
                             f16* Hhist0, unsigned* cnt) {
  int i = blockIdx.x * blockDim.x + threadIdx.x;
  if (i < 1024)      cnt[i] = 0u;
  if (i < VN_ * EN_) embN16[i] = (f16)embN[i];
  if (i < VS_ * ET_) embT16[i] = (f16)embT[i];
  if (i < 512) {                          // dyn init tiled [g][8]: hd | cd
    int g = i >> 3, j = i & 7;
    dynT[i] = (f16)((j < 4) ? dyn_init_h[g * 4 + j] : dyn_init_c[g * 4 + (j - 4)]);
  }
  if (i < B_ * H_) {                      // tiled: (b,k) -> (k>>2)*256 + b*4 + (k&3)
    int b = i >> 9, k = i & 511;
    Hhist0[(k >> 2) * 256 + b * 4 + (k & 3)] = (f16)hid_init[k];
  }
  __threadfence();
}

// ---- prev-occurrence table ----
__global__ void prev_kernel(const int* t_input, const int* s2d, int* prev) {
  int idx = blockIdx.x * blockDim.x + threadIdx.x;
  if (idx < B_ * T_) {
    int b = idx / T_, t = idx % T_;
    int tt = t_input[b * T_ + t];
    int p = -1;
    if (s2d[tt] != tt) {
      for (int q = t - 1; q >= 0; --q)
        if (t_input[b * T_ + q] == tt) { p = q; break; }
    }
    prev[t * B_ + b] = p;
  }
  __threadfence();
}

// resolve X-source (base+stride, f16 units) for step t, batch b.
// rc flags rows with pv == tprev (in flight when prefetched -> sc reload).
__device__ __forceinline__ void resolve(const RnnParams& p, bool isDyn, int t, int b,
                                        int tprev,
                                        const f16** aN, const f16** aX,
                                        int* sx, int* rc) {
  const int nt = p.n_input[b * T_ + t];
  aN[b] = p.embN16 + (size_t)nt * EN_;
  const int tt = p.t_input[b * T_ + t];
  const int pv = p.prev[t * B_ + b];
  rc[b] = (pv >= 0 && pv == tprev) ? 1 : 0;
  const int s2 = p.s2d[tt];
  if (!isDyn && s2 == tt) {               // static: embT row (pv==-1 -> rc==0)
    aX[b] = p.embT16 + (size_t)s2 * ET_;
    sx[b] = 4;
  } else if (pv >= 0) {                   // previous dyn state
    aX[b] = p.DynHist + (size_t)pv * 32768 + (size_t)b * 8;
    sx[b] = 512;
  } else {                                // init row
    aX[b] = p.dynT;
    sx[b] = 8;
  }
}

// ---- main persistent recurrent kernel ----
__global__ __launch_bounds__(NTHR_, 1) void rnn_main(RnnParams p) {
  const int blk  = blockIdx.x;
  const int tid  = threadIdx.x;
  const int wave = tid >> 6;
  const int lane = tid & 63;
  const bool isDyn = (blk >= NB_MAIN_);
  const int u0 = isDyn ? (blk - NB_MAIN_) * 4 : blk * 4;
  const int gb = blk - NB_MAIN_;          // dyn group (valid when isDyn)

  __threadfence();   // one-time: invalidate caches to the coherent point

  __shared__ float s_bias[16];
  __shared__ float s_scr[64][17];
  __shared__ const f16* s_aN[2][64];
  __shared__ const f16* s_aX[2][64];
  __shared__ int s_sx[2][64];
  __shared__ int s_rc[2][64];

  // ---- one-time: weights into registers ----
  // lane l supplies B-frag elems: B[k = s*32 + (l>>4)*8 + j][n = l&15]
  const int nIdx = lane & 15;
  const int ui = nIdx & 3, gate = nIdx >> 2;
  const int ko = (lane >> 4) * 8;
  f16x8 w[32];
  if (!isDyn) {
    const int r = gate * H_ + u0 + ui;
#pragma unroll
    for (int s = 0; s < 32; ++s) {
      const int k = s * 32 + ko;           // [0,256)=embN [256,512)=h_tensor [512,1024)=h
      const float* src = (k < 512) ? (p.W_ih + (size_t)r * 512 + k)
                                   : (p.W_hh + (size_t)r * 512 + (k - 512));
      f16x8 v;
#pragma unroll
      for (int j = 0; j < 8; ++j) v[j] = (f16)src[j];
      w[s] = v;
    }
  } else {
    const int r = gate * D_ + u0 + ui;
#pragma unroll
    for (int s = 0; s < 32; ++s) {
      const int k = s * 32 + ko;           // [0,256)=embN [256,768)=h [768,1024)=hd_prev
      const float* src = (k < 768) ? (p.Wd_ih + (size_t)r * 768 + k)
                                   : (p.Wd_hh + (size_t)r * 256 + (k - 768));
      f16x8 v;
#pragma unroll
      for (int j = 0; j < 8; ++j) v[j] = (f16)src[j];
      w[s] = v;
    }
  }
  if (tid < 16) {
    int g2 = tid >> 2, un2 = tid & 3;
    s_bias[tid] = isDyn ? (p.bd_ih[g2 * D_ + u0 + un2] + p.bd_hh[g2 * D_ + u0 + un2])
                        : (p.b_ih[g2 * H_ + u0 + un2] + p.b_hh[g2 * H_ + u0 + un2]);
  }
  float creg[4] = {0.f, 0.f, 0.f, 0.f};
  if (tid < 64 && !isDyn) {
#pragma unroll
    for (int un = 0; un < 4; ++un) creg[un] = p.cell_init[u0 + un];
  }
  if (tid < 64)
    resolve(p, isDyn, 0, tid, -1, s_aN[0], s_aX[0], s_sx[0], s_rc[0]);
  __syncthreads();

  // ---- pre-loop prefetch for t=0 ----
  const int b = (wave << 4) + (lane & 15);
  const int gq = ko >> 2;                 // lane group offset within slice
  f16x8 pf[16];      // [0..7]=embN slices, [8..15]=X-panel (h_tensor / hd)
  f16x4 cvq = {0, 0, 0, 0};
  {
    const f16* pN = s_aN[0][b];
    const f16* bX = s_aX[0][b];
    const int sx = s_sx[0][b];
#pragma unroll
    for (int i = 0; i < 8; ++i) pf[i] = *(const f16x8*)(pN + i * 32 + ko);
#pragma unroll
    for (int i = 0; i < 8; ++i) {
      const int g0 = i * 8 + gq;
      union { f16x4 q[2]; f16x8 o; } u;
      u.q[0] = *(const f16x4*)(bX + (size_t)g0 * sx);
      u.q[1] = *(const f16x4*)(bX + (size_t)(g0 + 1) * sx);
      pf[8 + i] = u.o;
    }
    if (isDyn && tid < 64)
      cvq = *(const f16x4*)(s_aX[0][tid] + 4 + (size_t)gb * s_sx[0][tid]);
  }
  // tiled-h per-lane base (f16 units)
  const int hoff = (gq << 8) + (b << 2);

  for (int t = 0; t < T_; ++t) {
    const int pb = t & 1;

    // ---- load h[t] from tiled layout: 2x8B per slice ----
    const f16* pH2 = p.Hhist + (size_t)t * 32768 + hoff;
    f16x8 hh[16];
#pragma unroll
    for (int i = 0; i < 16; ++i) {
      f16x4* h4 = (f16x4*)&hh[i];
      h4[0] = *(const f16x4*)(pH2 + i * 2048);
      h4[1] = *(const f16x4*)(pH2 + i * 2048 + 256);
    }

    // ---- rare fixup: X rows with pv == t-1 (sc-hardened batched reload) ----
    {
      const int need = s_rc[pb][b];
      if (__any(need)) {
        f16x4 lo[8], hi[8];
        if (need) {
          const f16* bX = s_aX[pb][b];
          const int sx = s_sx[pb][b];
#pragma unroll
          for (int i = 0; i < 8; ++i) {
            const int g0 = i * 8 + gq;
            asm volatile("global_load_dwordx2 %0, %1, off sc0 sc1"
                         : "=&v"(lo[i]) : "v"(bX + (size_t)g0 * sx));
            asm volatile("global_load_dwordx2 %0, %1, off sc0 sc1"
                         : "=&v"(hi[i]) : "v"(bX + (size_t)(g0 + 1) * sx));
          }
        }
        asm volatile("s_waitcnt vmcnt(0)" ::: "memory");
        __builtin_amdgcn_sched_barrier(0);
        if (need) {
#pragma unroll
          for (int i = 0; i < 8; ++i) {
            union { f16x4 q[2]; f16x8 o; } u;
            u.q[0] = lo[i]; u.q[1] = hi[i];
            pf[8 + i] = u.o;
          }
        }
      }
    }

    // ---- 32 MFMAs (x-part first; hh flight hides under them) ----
    f32x4 ac[4] = {{0,0,0,0},{0,0,0,0},{0,0,0,0},{0,0,0,0}};
    if (!isDyn) {
#pragma unroll
      for (int i = 0; i < 8; ++i)
        ac[i & 3] = __builtin_amdgcn_mfma_f32_16x16x32_f16(pf[i], w[i], ac[i & 3], 0, 0, 0);
#pragma unroll
      for (int i = 0; i < 8; ++i)
        ac[i & 3] = __builtin_amdgcn_mfma_f32_16x16x32_f16(pf[8 + i], w[8 + i], ac[i & 3], 0, 0, 0);
#pragma unroll
      for (int i = 0; i < 16; ++i)
        ac[i & 3] = __builtin_amdgcn_mfma_f32_16x16x32_f16(hh[i], w[16 + i], ac[i & 3], 0, 0, 0);
    } else {
#pragma unroll
      for (int i = 0; i < 8; ++i)
        ac[i & 3] = __builtin_amdgcn_mfma_f32_16x16x32_f16(pf[i], w[i], ac[i & 3], 0, 0, 0);
#pragma unroll
      for (int i = 0; i < 8; ++i)
        ac[i & 3] = __builtin_amdgcn_mfma_f32_16x16x32_f16(pf[8 + i], w[24 + i], ac[i & 3], 0, 0, 0);
#pragma unroll
      for (int i = 0; i < 16; ++i)
        ac[i & 3] = __builtin_amdgcn_mfma_f32_16x16x32_f16(hh[i], w[8 + i], ac[i & 3], 0, 0, 0);
    }
    f32x4 acc = (ac[0] + ac[1]) + (ac[2] + ac[3]);
    // D[m][n]: m = (lane>>4)*4 + j (batch in tile), n = lane&15 (gate row)
#pragma unroll
    for (int j = 0; j < 4; ++j)
      s_scr[(wave << 4) + ((lane >> 4) << 2) + j][lane & 15] = acc[j];
    lds_barrier();                                   // #1 (lgkm-only)

    if (tid < 64) {
      // ---- epilogue (wave 0): one batch per thread, 4 units ----
      const int eb = tid;
      if (isDyn) {                                   // rare cd fixup (pv == t-1)
        const int cneed = s_rc[pb][eb];
        if (__any(cneed)) {
          if (cneed)
            cvq = scload8h(s_aX[pb][eb] + 4 + (size_t)gb * s_sx[pb][eb]);
          __builtin_amdgcn_sched_barrier(0);
        }
      }
      float g[16];
#pragma unroll
      for (int n = 0; n < 16; ++n) g[n] = s_scr[eb][n] + s_bias[n];
      if (!isDyn) {
        union { f16 h[4]; unsigned long long u; } pk;
#pragma unroll
        for (int un = 0; un < 4; ++un) {
          float c = sigm(g[4 + un]) * creg[un] + sigm(g[un]) * tanh_fast(g[8 + un]);
          creg[un] = c;
          float h = sigm(g[12 + un]) * tanh_fast(c);
          pk.h[un] = (f16)h;
        }
        // tiled h publish: 64 lanes x 8B = contiguous, fully-covered 512B
        cstore8(&p.Hhist[(size_t)(t + 1) * 32768 + (size_t)(u0 >> 2) * 256
                         + (size_t)eb * 4], pk.u);
      } else {
        const float cold[4] = {(float)cvq[0], (float)cvq[1],
                               (float)cvq[2], (float)cvq[3]};
        f16x8 pk;                                   // [0..3]=hd, [4..7]=cd
#pragma unroll
        for (int un = 0; un < 4; ++un) {
          float c = sigm(g[4 + un]) * cold[un] + sigm(g[un]) * tanh_fast(g[8 + un]);
          float h = sigm(g[12 + un]) * tanh_fast(c);
          pk[un] = (f16)h;
          pk[4 + un] = (f16)c;
        }
        // unconditional merged publish: 64 lanes x 16B = contiguous 1KB
        cstore16h(&p.DynHist[(size_t)t * 32768 + (size_t)gb * 512
                             + (size_t)eb * 8], pk);
      }
    } else if (tid < 128 && t + 1 < T_) {
      // ---- wave 1: resolve next step's pointers concurrently ----
      resolve(p, isDyn, t + 1, tid - 64, t,
              s_aN[pb ^ 1], s_aX[pb ^ 1], s_sx[pb ^ 1], s_rc[pb ^ 1]);
    }
    lds_barrier();                                   // #2 (lgkm-only; no drain)

    if (t + 1 < T_) {
      // ---- wave0-private drain + arrive (others go prefetch) ----
      if (wave == 0) {
        asm volatile("s_waitcnt vmcnt(0)" ::: "memory");
        if (tid == 0)
          __hip_atomic_fetch_add(&p.cnt[(blk & (NSH_ - 1)) << 4], 1u,
                                 __ATOMIC_RELAXED, __HIP_MEMORY_SCOPE_AGENT);
      }
      // ---- prefetch step-independent slices for t+1 (flies during poll) ----
      {
        const f16* pN2 = s_aN[pb ^ 1][b];
        const f16* bX2 = s_aX[pb ^ 1][b];
        const int sx2 = s_sx[pb ^ 1][b];
#pragma unroll
        for (int i = 0; i < 8; ++i) pf[i] = *(const f16x8*)(pN2 + i * 32 + ko);
#pragma unroll
        for (int i = 0; i < 8; ++i) {
          const int g0 = i * 8 + gq;
          union { f16x4 q[2]; f16x8 o; } u;
          u.q[0] = *(const f16x4*)(bX2 + (size_t)g0 * sx2);
          u.q[1] = *(const f16x4*)(bX2 + (size_t)(g0 + 1) * sx2);
          pf[8 + i] = u.o;
        }
        if (isDyn && tid < 64)
          cvq = *(const f16x4*)(s_aX[pb ^ 1][tid] + 4
                                + (size_t)gb * s_sx[pb ^ 1][tid]);
      }
      // ---- wave 1 polls (1 lane : 1 shard line) ----
      if (wave == 1) {
        const unsigned tgt = (unsigned)(t + 1) * PER_SHARD_;
        unsigned it = 0;
        while (__hip_atomic_load(&p.cnt[lane << 4], __ATOMIC_RELAXED,
                                 __HIP_MEMORY_SCOPE_AGENT) < tgt &&
               ++it < POLL_CAP_)
          __builtin_amdgcn_s_sleep(1);
      }
      lds_barrier();                                 // #3 release (lgkm-only)
    }
  }

  // ---- bulk out pass (main blocks; own Hhist data only) ----
  asm volatile("s_waitcnt vmcnt(0)" ::: "memory");
  if (!isDyn) {
    const int ob = tid & 63;               // batch (lane-consecutive -> coalesced read)
    const int tq = tid >> 6;               // t quarter
    const int gm = u0 >> 2;
    for (int i = 0; i < 64; ++i) {
      const int t = (tq << 6) + i;
      f16x4 hv = *(const f16x4*)(p.Hhist + (size_t)(t + 1) * 32768
                                 + (size_t)gm * 256 + (size_t)ob * 4);
      float4 o;
      o.x = (float)hv[0]; o.y = (float)hv[1]; o.z = (float)hv[2]; o.w = (float)hv[3];
      *(float4*)&p.out[((size_t)ob * T_ + t) * H_ + u0] = o;
    }
  }
}

extern "C" void kernel_launch(void* const* d_in, const int* in_sizes, int n_in,
                              void* d_out, int out_size, void* d_ws, size_t ws_size,
                              hipStream_t stream) {
  (void)in_sizes; (void)n_in; (void)out_size;
  const int* n_input   = (const int*)d_in[0];
  const int* t_input   = (const int*)d_in[1];
  const int* s2d       = (const int*)d_in[3];
  const float* embN    = (const float*)d_in[5];
  const float* embT    = (const float*)d_in[6];
  const float* W_ih    = (const float*)d_in[7];
  const float* W_hh    = (const float*)d_in[8];
  const float* b_ih    = (const float*)d_in[9];
  const float* b_hh    = (const float*)d_in[10];
  const float* Wd_ih   = (const float*)d_in[11];
  const float* Wd_hh   = (const float*)d_in[12];
  const float* bd_ih   = (const float*)d_in[13];
  const float* bd_hh   = (const float*)d_in[14];
  const float* hid_init  = (const float*)d_in[15];
  const float* cell_init = (const float*)d_in[16];
  const float* dyn_init_h = (const float*)d_in[17];
  const float* dyn_init_c = (const float*)d_in[18];

  char* ws = (char*)d_ws;
  unsigned* cnt  = (unsigned*)(ws + OFF_CNT);
  f16* embN16    = (f16*)(ws + OFF_EMBN);
  f16* embT16    = (f16*)(ws + OFF_EMBT);
  f16* dynT      = (f16*)(ws + OFF_DIT);
  int* prev      = (int*)(ws + OFF_PREV);
  f16* Hhist     = (f16*)(ws + OFF_HH);
  f16* DynHist   = (f16*)(ws + OFF_DH);
  if (ws_size < WS_NEED) return;

  setup_kernel<<<dim3((VN_ * EN_ + NTHR_ - 1) / NTHR_), dim3(NTHR_), 0, stream>>>(
      embN, embT, hid_init, dyn_init_h, dyn_init_c,
      embN16, embT16, dynT, Hhist, cnt);
  prev_kernel<<<dim3((B_ * T_ + NTHR_ - 1) / NTHR_), dim3(NTHR_), 0, stream>>>(
      t_input, s2d, prev);

  RnnParams prm;
  prm.n_input = n_input; prm.t_input = t_input; prm.s2d = s2d;
  prm.W_ih = W_ih; prm.W_hh = W_hh; prm.b_ih = b_ih; prm.b_hh = b_hh;
  prm.Wd_ih = Wd_ih; prm.Wd_hh = Wd_hh; prm.bd_ih = bd_ih; prm.bd_hh = bd_hh;
  prm.cell_init = cell_init;
  prm.embN16 = embN16; prm.embT16 = embT16; prm.dynT = dynT;
  prm.prev = prev; prm.Hhist = Hhist; prm.DynHist = DynHist;
  prm.out = (float*)d_out; prm.cnt = cnt;

  void* args[] = { &prm };
  hipError_t e = hipLaunchCooperativeKernel((const void*)rnn_main,
                                            dim3(NBLK_), dim3(NTHR_), args, 0, stream);
  if (e != hipSuccess) {
    rnn_main<<<dim3(NBLK_), dim3(NTHR_), 0, stream>>>(prm);
  }
}